// Round 9
// baseline (1548.106 us; speedup 1.0000x reference)
//
#include <hip/hip_runtime.h>

#define NNODES 50000
#define NEDGES 800000
#define F 128
#define NREL 8
#define NOUT 1152   // 9*128: 8 relations + self-loop
#define NBKT 98     // ceil(50000 / 512) coarse buckets
#define BSH 9       // 512 nodes per bucket
#define SEG 16384   // fixed ebuf segment per bucket (max bucket ~8.5k)
#define NTILES 391  // ceil(50000/128)
#define GEMM_BLOCKS (8 * 9 * 49)   // 3528 (XCD-swizzled)
#define CSR_BLOCKS 196

typedef float f32x4 __attribute__((ext_vector_type(4)));
typedef float f32x2 __attribute__((ext_vector_type(2)));

typedef __attribute__((address_space(3))) void lds_void;
typedef const __attribute__((address_space(1))) void glb_void;
__device__ __forceinline__ void gll16(const void* g, void* l) {
  // async global->LDS, 16B per lane; LDS dest = wave-uniform base + lane*16
  __builtin_amdgcn_global_load_lds(
      (glb_void*)(unsigned long long)g,
      (lds_void*)(unsigned)(unsigned long long)l, 16, 0, 0);
}

// ========== fused prep: zero | cvt(fp8) | prepw(W1) | prepw(W2) =============
#define PREP_ZERO  33
#define PREP_CVT   6250    // 50000*128/4 / 256 uints
#define PREP_W     144     // 1152*128/4 / 256 uints per weight set
__global__ __launch_bounds__(256)
void k_prep(const float* __restrict__ in_feat, unsigned* __restrict__ feat0,
            const float* __restrict__ W1, const float* __restrict__ W1s,
            unsigned* __restrict__ Wt1,
            const float* __restrict__ W2, const float* __restrict__ W2s,
            unsigned* __restrict__ Wt2,
            float* __restrict__ pooled_p, int* __restrict__ bcur) {
  const int b = blockIdx.x, t = threadIdx.x;
  if (b < 32) {
    pooled_p[b * 256 + t] = 0.f;          // 32*256 = 8192 = 64*128
  } else if (b < PREP_ZERO) {
    if (t <= NBKT) bcur[t] = 0;           // bcur[98] (+1 spare)
  } else if (b < PREP_ZERO + PREP_CVT) {
    int i = (b - PREP_ZERO) * 256 + t;    // exactly 1.6M float4 -> uint
    float4 v = ((const float4*)in_feat)[i];
    unsigned pk = 0;
    pk = __builtin_amdgcn_cvt_pk_fp8_f32(v.x, v.y, pk, false);
    pk = __builtin_amdgcn_cvt_pk_fp8_f32(v.z, v.w, pk, true);
    feat0[i] = pk;
  } else {
    int w2 = (b >= PREP_ZERO + PREP_CVT + PREP_W);
    int idx = (b - PREP_ZERO - PREP_CVT - (w2 ? PREP_W : 0)) * 256 + t;
    int n = idx >> 5, k0 = (idx & 31) * 4;   // Wt[n][k0..k0+3]
    int r = n >> 7, c = n & 127;
    const float* Wr = w2 ? W2 : W1;
    const float* Ws = w2 ? W2s : W1s;
    float v0, v1, v2, v3;
    if (r < NREL) {
      v0 = Wr[((size_t)(r * F + k0 + 0)) * F + c];
      v1 = Wr[((size_t)(r * F + k0 + 1)) * F + c];
      v2 = Wr[((size_t)(r * F + k0 + 2)) * F + c];
      v3 = Wr[((size_t)(r * F + k0 + 3)) * F + c];
    } else {
      v0 = Ws[(size_t)(k0 + 0) * F + c];
      v1 = Ws[(size_t)(k0 + 1) * F + c];
      v2 = Ws[(size_t)(k0 + 2) * F + c];
      v3 = Ws[(size_t)(k0 + 3) * F + c];
    }
    unsigned pk = 0;
    pk = __builtin_amdgcn_cvt_pk_fp8_f32(v0, v1, pk, false);
    pk = __builtin_amdgcn_cvt_pk_fp8_f32(v2, v3, pk, true);
    (w2 ? Wt2 : Wt1)[idx] = pk;
  }
}

// ====== GEMM: xrs[50000][1152](fp8) = A[50000][128] @ Wt^T  (fp8 MFMA) ======
// R20: full fp8 datapath. As/Bs 16KB each (LDS 33.5KB -> 4 blocks/CU).
// 8B-granular XOR swizzle; mfma_f32_16x16x32_fp8_fp8, swapped operands.
// Epilogue LDS-transpose stores (R16). doCsr blocks [0,196): CSR scatter.
__global__ __launch_bounds__(512, 8)
void gemm_xrs(const unsigned char* __restrict__ A,
              const unsigned char* __restrict__ Wt,
              unsigned char* __restrict__ xrs, int doCsr,
              const int* __restrict__ src, const int* __restrict__ dst,
              const int* __restrict__ et, int* __restrict__ bcur,
              int* __restrict__ ebuf) {
  __shared__ uint4 As[1024];  // 128 rows x 8 uint4 (fp8), xor-swizzled
  __shared__ uint4 Bs[1024];
  __shared__ int lhist[NBKT];
  __shared__ int lbase[NBKT];
  const int tid = threadIdx.x;

  if (doCsr && blockIdx.x < CSR_BLOCKS) {
    // ---- coarse scatter: record = (dst_local<<19)|(src<<3)|et ----
    if (tid < NBKT) lhist[tid] = 0;
    __syncthreads();
    int e0 = blockIdx.x * 4096;
    int rec[8], cc[8], lr[8];
#pragma unroll
    for (int i = 0; i < 8; ++i) {
      int e = e0 + tid + i * 512;
      if (e < NEDGES) {
        int d = dst[e];
        cc[i] = d >> BSH;
        rec[i] = ((d & 511) << 19) | (src[e] << 3) | et[e];
        lr[i] = atomicAdd(&lhist[cc[i]], 1);
      } else {
        cc[i] = -1;
      }
    }
    __syncthreads();
    if (tid < NBKT && lhist[tid] > 0) lbase[tid] = atomicAdd(&bcur[tid], lhist[tid]);
    __syncthreads();
#pragma unroll
    for (int i = 0; i < 8; ++i)
      if (cc[i] >= 0) ebuf[cc[i] * SEG + lbase[cc[i]] + lr[i]] = rec[i];
    return;
  }

  const int id = blockIdx.x - (doCsr ? CSR_BLOCKS : 0);
  const int x = id & 7, j = id >> 3;
  const int tile = (j / 9) * 8 + x;
  const int cb = j % 9;
  if (tile >= NTILES) return;
  const int row0 = tile * 128;

  const int lane = tid & 63;
  const int w = tid >> 6;           // 0..7
  const int i16 = lane & 15, q = lane >> 4;
  const int mbase = (w & 3) * 32, nbase = (w >> 2) * 64;

  // Stage fp8 tiles via global_load_lds: slot L (r=L>>3, chunk c8s=L&7)
  // receives source chunk c8s ^ (r&7)  (involution matches the read side).
#pragma unroll
  for (int i = 0; i < 2; ++i) {
    int L = tid + i * 512;
    int r = L >> 3, c8s = L & 7;
    int c8 = c8s ^ (r & 7);
    int agr = row0 + r; if (agr >= NNODES) agr = NNODES - 1;
    gll16((const void*)(A + (size_t)agr * F + c8 * 16), (void*)&As[L]);
    gll16((const void*)(Wt + ((size_t)cb * 128 + r) * F + c8 * 16), (void*)&Bs[L]);
  }
  __syncthreads();

  f32x4 acc[2][4];
#pragma unroll
  for (int a = 0; a < 2; ++a)
#pragma unroll
    for (int b = 0; b < 4; ++b) acc[a][b] = (f32x4)0.f;

  const char* Ab = (const char*)As;
  const char* Bb = (const char*)Bs;
#pragma unroll
  for (int c = 0; c < 4; ++c) {
    // lane holds 8 fp8 K-elems: k = c*32 + q*8 .. +7
    const int ch = c * 2 + (q >> 1);   // 16B chunk index of that K-slice
    const int h8 = (q & 1) << 3;       // 8B half within chunk
    long af[2], bfr[4];
#pragma unroll
    for (int mi = 0; mi < 2; ++mi) {
      int r = mbase + mi * 16 + i16;
      af[mi] = *(const long*)(Ab + r * 128 + ((ch ^ (r & 7)) << 4) + h8);
    }
#pragma unroll
    for (int ni = 0; ni < 4; ++ni) {
      int r = nbase + ni * 16 + i16;
      bfr[ni] = *(const long*)(Bb + r * 128 + ((ch ^ (r & 7)) << 4) + h8);
    }
    // Swapped operands: D[m=weight feature][n=node row]
#pragma unroll
    for (int mi = 0; mi < 2; ++mi)
#pragma unroll
      for (int ni = 0; ni < 4; ++ni)
        acc[mi][ni] = __builtin_amdgcn_mfma_f32_16x16x32_fp8_fp8(
            bfr[ni], af[mi], acc[mi][ni], 0, 0, 0);
  }

  // ---- Epilogue with LDS transpose (R16) ----
  unsigned pkv[2][4];
#pragma unroll
  for (int mi = 0; mi < 2; ++mi)
#pragma unroll
    for (int ni = 0; ni < 4; ++ni) {
      f32x4 v = acc[mi][ni];
      unsigned pk = 0;
      pk = __builtin_amdgcn_cvt_pk_fp8_f32(v[0], v[1], pk, false);
      pk = __builtin_amdgcn_cvt_pk_fp8_f32(v[2], v[3], pk, true);
      pkv[mi][ni] = pk;
    }

  __syncthreads();  // all waves done reading As; reuse As as staging (16KB)
  unsigned* sbuf = (unsigned*)As;  // [128 nodes][32 dwords] = 16KB
  {
    const int dbase = (nbase >> 2) + q;
#pragma unroll
    for (int mi = 0; mi < 2; ++mi) {
      int nl = mbase + mi * 16 + i16;
      int sw = (nl & 7) << 2;
      int vb_ = nl * 32;
#pragma unroll
      for (int ni = 0; ni < 4; ++ni)
        sbuf[vb_ + ((dbase + ni * 4) ^ sw)] = pkv[mi][ni];
    }
  }
  __syncthreads();

#pragma unroll
  for (int k = 0; k < 2; ++k) {
    int nl = k * 64 + (tid >> 3);
    int ch = tid & 7;
    int d0 = (ch * 4) ^ ((nl & 7) << 2);
    uint4 v = *(const uint4*)&sbuf[nl * 32 + d0];
    int row = row0 + nl;
    if (row < NNODES)
      *(uint4*)(xrs + (size_t)row * NOUT + cb * 128 + ch * 16) = v;
  }
}

// ========== aggregate R23: bucket-streaming with LDS f32 accumulators ======
// One block per half-bucket (196 blocks x 512 thr): 256 nodes' accumulators
// live in LDS (pad-9 octet layout: slot = local*143 + (f>>3)*9 + (f&7) ->
// ds_add_f32 conflict-free within a 16-lane group). Streams the bucket's
// ebuf segment directly (no fsort/rowptr/edata): rec -> filter by half ->
// gather 128B xrs row (16 lanes x uint2, quad-edge groups, 8-deep) ->
// 8 LDS float-atomics per lane.
// R23 FIX: edge loop is WAVE-STRIDED (base = wv*64, step 512) - R22 had all
// 8 waves scanning the same chunks (8x overcount, absmax 0.5).
// Epilogue: self-loop + bias + relu; then pack fp8 h (layer 1) or pooled
// reduce + spread atomics (layer 2).
__global__ __launch_bounds__(512, 1)
void k_agg(const unsigned char* __restrict__ xrs,
           const int* __restrict__ ebuf, const int* __restrict__ bcur,
           const float* __restrict__ bias, unsigned char* __restrict__ hout,
           float* __restrict__ pooled_p) {
  __shared__ float accL[256 * 143];   // 146,432 B
  const int tid = threadIdx.x;
  const int B = blockIdx.x >> 1, half = blockIdx.x & 1;
  const int n0 = (B << BSH) + half * 256;
  const int cnt = bcur[B];
  const int sbeg = B * SEG;
  const int lane = tid & 63;
  const int wv = tid >> 6;            // 0..7 — wave owns chunks wv, wv+8, ...
  const int g = lane >> 4, s = lane & 15;

  for (int i = tid; i < 256 * 143; i += 512) accL[i] = 0.f;
  __syncthreads();

  for (int base = wv * 64; base < cnt; base += 512) {
    int my = (base + lane < cnt) ? ebuf[sbeg + base + lane] : -1;
#pragma unroll
    for (int qb = 0; qb < 16; qb += 8) {
      uint2 v[8]; int loc[8]; bool ok[8];
#pragma unroll
      for (int k = 0; k < 8; ++k) {
        int rec = __shfl(my, 4 * (qb + k) + g, 64);
        unsigned dl = ((unsigned)rec) >> 19;
        ok[k] = ((dl >> 8) == (unsigned)half);   // sentinel -1 fails both
        loc[k] = dl & 255;
        int off = ((rec >> 3) & 0xFFFF) * NOUT + (rec & 7) * F;
        if (ok[k]) v[k] = *(const uint2*)(xrs + (size_t)off + s * 8);
      }
#pragma unroll
      for (int k = 0; k < 8; ++k) {
        if (ok[k]) {
          f32x2 l0 = __builtin_amdgcn_cvt_pk_f32_fp8(v[k].x, false);
          f32x2 h0 = __builtin_amdgcn_cvt_pk_f32_fp8(v[k].x, true);
          f32x2 l1 = __builtin_amdgcn_cvt_pk_f32_fp8(v[k].y, false);
          f32x2 h1 = __builtin_amdgcn_cvt_pk_f32_fp8(v[k].y, true);
          float* a = &accL[loc[k] * 143 + s * 9];
          atomicAdd(a + 0, l0[0]); atomicAdd(a + 1, l0[1]);
          atomicAdd(a + 2, h0[0]); atomicAdd(a + 3, h0[1]);
          atomicAdd(a + 4, l1[0]); atomicAdd(a + 5, l1[1]);
          atomicAdd(a + 6, h1[0]); atomicAdd(a + 7, h1[1]);
        }
      }
    }
  }
  __syncthreads();

  // ---- epilogue pass 1: self-loop + bias + relu (thread -> node, 64 feats)
  const int ln = tid >> 1, hh = tid & 1;
  const int node = n0 + ln;
  float vals[64];
  if (node < NNODES) {
    const unsigned* sp =
        (const unsigned*)(xrs + (size_t)node * NOUT + NREL * F + hh * 64);
    const float4* bp = (const float4*)(bias + hh * 64);
#pragma unroll
    for (int o = 0; o < 8; ++o) {   // octet o: feats hh*64 + o*8 .. +7
      float* a = &accL[ln * 143 + (8 * hh + o) * 9];
      unsigned sv0 = sp[o * 2], sv1 = sp[o * 2 + 1];
      f32x2 l0 = __builtin_amdgcn_cvt_pk_f32_fp8(sv0, false);
      f32x2 h0 = __builtin_amdgcn_cvt_pk_f32_fp8(sv0, true);
      f32x2 h1lo = __builtin_amdgcn_cvt_pk_f32_fp8(sv1, false);
      f32x2 h1hi = __builtin_amdgcn_cvt_pk_f32_fp8(sv1, true);
      float4 b0 = bp[o * 2], b1 = bp[o * 2 + 1];
      vals[o * 8 + 0] = fmaxf(a[0] + l0[0] + b0.x, 0.f);
      vals[o * 8 + 1] = fmaxf(a[1] + l0[1] + b0.y, 0.f);
      vals[o * 8 + 2] = fmaxf(a[2] + h0[0] + b0.z, 0.f);
      vals[o * 8 + 3] = fmaxf(a[3] + h0[1] + b0.w, 0.f);
      vals[o * 8 + 4] = fmaxf(a[4] + h1lo[0] + b1.x, 0.f);
      vals[o * 8 + 5] = fmaxf(a[5] + h1lo[1] + b1.y, 0.f);
      vals[o * 8 + 6] = fmaxf(a[6] + h1hi[0] + b1.z, 0.f);
      vals[o * 8 + 7] = fmaxf(a[7] + h1hi[1] + b1.w, 0.f);
    }
  }

  if (hout) {
    if (node < NNODES) {
      unsigned pk[16];
#pragma unroll
      for (int d = 0; d < 16; ++d) {
        unsigned p = 0;
        p = __builtin_amdgcn_cvt_pk_fp8_f32(vals[d * 4 + 0], vals[d * 4 + 1], p, false);
        p = __builtin_amdgcn_cvt_pk_fp8_f32(vals[d * 4 + 2], vals[d * 4 + 3], p, true);
        pk[d] = p;
      }
      uint4* d4 = (uint4*)(hout + (size_t)node * F + hh * 64);
#pragma unroll
      for (int i = 0; i < 4; ++i)
        d4[i] = make_uint4(pk[i * 4], pk[i * 4 + 1], pk[i * 4 + 2], pk[i * 4 + 3]);
    }
  } else {
    // write relu'd values back (invalid nodes stay 0), then pool per feat
    if (node < NNODES) {
#pragma unroll
      for (int o = 0; o < 8; ++o) {
        float* a = &accL[ln * 143 + (8 * hh + o) * 9];
#pragma unroll
        for (int j = 0; j < 8; ++j) a[j] = vals[o * 8 + j];
      }
    }
    __syncthreads();
    int f = tid & 127, G = tid >> 7;   // 4 groups x 64 nodes
    int o9 = (f >> 3) * 9 + (f & 7);
    float sum = 0.f;
#pragma unroll 16
    for (int l = G * 64; l < G * 64 + 64; ++l)
      sum += accL[l * 143 + o9];
    atomicAdd(&pooled_p[(blockIdx.x & 63) * 128 + f], sum);
  }
}

// ================== final: reduce 64x128 partials + fc + sigmoid ============
__global__ __launch_bounds__(128)
void k_final(const float* __restrict__ pooled_p, const float* __restrict__ fcw,
             const float* __restrict__ fcb, float* __restrict__ out) {
  __shared__ float s[128];
  int t = threadIdx.x;
  float acc = 0.f;
#pragma unroll 8
  for (int k = 0; k < 64; ++k) acc += pooled_p[k * 128 + t];
  s[t] = acc * (1.0f / (float)NNODES) * fcw[t];
  __syncthreads();
  if (t == 0) {
    float v = 0.f;
    for (int i = 0; i < 128; ++i) v += s[i];
    v += fcb[0];
    out[0] = 1.f / (1.f + expf(-v));
  }
}

// ============================================================================
extern "C" void kernel_launch(void* const* d_in, const int* in_sizes, int n_in,
                              void* d_out, int out_size, void* d_ws, size_t ws_size,
                              hipStream_t stream) {
  const float* in_feat = (const float*)d_in[0];
  const float* W1      = (const float*)d_in[1];
  const float* W1s     = (const float*)d_in[2];
  const float* b1      = (const float*)d_in[3];
  const float* W2      = (const float*)d_in[4];
  const float* W2s     = (const float*)d_in[5];
  const float* b2      = (const float*)d_in[6];
  const float* fcw     = (const float*)d_in[7];
  const float* fcb     = (const float*)d_in[8];
  const int*   src     = (const int*)d_in[9];
  const int*   dst     = (const int*)d_in[10];
  const int*   et      = (const int*)d_in[11];
  float* out = (float*)d_out;

  // Workspace (~72 MB)
  unsigned char* xrs = (unsigned char*)d_ws;              // [50000][1152] fp8
  unsigned char* feat0 = xrs + (size_t)NNODES * NOUT;     // [50000][128] fp8
  unsigned char* h1  = feat0 + (size_t)NNODES * F;        // [50000][128] fp8
  unsigned char* Wt1 = h1 + (size_t)NNODES * F;           // [1152][128] fp8
  unsigned char* Wt2 = Wt1 + (size_t)NOUT * F;            // [1152][128] fp8
  float* pooled_p = (float*)(Wt2 + (size_t)NOUT * F);     // [64][128]
  int*   bcur   = (int*)(pooled_p + 64 * 128);            // [NBKT+1]
  int*   ebuf   = bcur + NBKT + 1;                        // [NBKT*SEG]

  // fused prep: zero(pooled_p,bcur) | feat cvt fp8 | weight prep x2
  k_prep<<<PREP_ZERO + PREP_CVT + 2 * PREP_W, 256, 0, stream>>>(
      in_feat, (unsigned*)feat0, W1, W1s, (unsigned*)Wt1,
      W2, W2s, (unsigned*)Wt2, pooled_p, bcur);

  // Layer 1 GEMM with CSR-scatter fused (scatter hidden under GEMM)
  gemm_xrs<<<CSR_BLOCKS + GEMM_BLOCKS, 512, 0, stream>>>(
      feat0, Wt1, xrs, 1, src, dst, et, bcur, ebuf);
  k_agg<<<2 * NBKT, 512, 0, stream>>>(xrs, ebuf, bcur, b1, h1, nullptr);
  // Layer 2 (pooling fused into aggregate; h2 never materialized)
  gemm_xrs<<<GEMM_BLOCKS, 512, 0, stream>>>(
      h1, Wt2, xrs, 0, src, dst, et, bcur, ebuf);
  k_agg<<<2 * NBKT, 512, 0, stream>>>(xrs, ebuf, bcur, b2, nullptr, pooled_p);

  // Reduce partials + fc + sigmoid
  k_final<<<1, 128, 0, stream>>>(pooled_p, fcw, fcb, out);
}

// Round 10
// 203.742 us; speedup vs baseline: 7.5984x; 7.5984x over previous
//
#include <hip/hip_runtime.h>

#define NNODES 50000
#define NEDGES 800000
#define F 128
#define NREL 8
#define NOUT 1152   // 9*128: 8 relations + self-loop
#define NBKT 98     // ceil(50000 / 512) coarse buckets
#define BSH 9       // 512 nodes per bucket
#define SEG 16384   // fixed ebuf segment per bucket (max bucket ~8.5k)
#define NTILES 391  // ceil(50000/128)
#define GEMM_BLOCKS (8 * 9 * 49)   // 3528 (XCD-swizzled)
#define CSR_BLOCKS 196

typedef float f32x4 __attribute__((ext_vector_type(4)));
typedef float f32x2 __attribute__((ext_vector_type(2)));

typedef __attribute__((address_space(3))) void lds_void;
typedef const __attribute__((address_space(1))) void glb_void;
__device__ __forceinline__ void gll16(const void* g, void* l) {
  // async global->LDS, 16B per lane; LDS dest = wave-uniform base + lane*16
  __builtin_amdgcn_global_load_lds(
      (glb_void*)(unsigned long long)g,
      (lds_void*)(unsigned)(unsigned long long)l, 16, 0, 0);
}

// ========== fused prep: zero | cvt(fp8) | prepw(W1) | prepw(W2) =============
#define PREP_ZERO  33
#define PREP_CVT   6250    // 50000*128/4 / 256 uints
#define PREP_W     144     // 1152*128/4 / 256 uints per weight set
__global__ __launch_bounds__(256)
void k_prep(const float* __restrict__ in_feat, unsigned* __restrict__ feat0,
            const float* __restrict__ W1, const float* __restrict__ W1s,
            unsigned* __restrict__ Wt1,
            const float* __restrict__ W2, const float* __restrict__ W2s,
            unsigned* __restrict__ Wt2,
            float* __restrict__ pooled_p, int* __restrict__ bcur) {
  const int b = blockIdx.x, t = threadIdx.x;
  if (b < 32) {
    pooled_p[b * 256 + t] = 0.f;          // 32*256 = 8192 = 64*128
  } else if (b < PREP_ZERO) {
    if (t <= NBKT) bcur[t] = 0;           // bcur[98] (+1 spare)
  } else if (b < PREP_ZERO + PREP_CVT) {
    int i = (b - PREP_ZERO) * 256 + t;    // exactly 1.6M float4 -> uint
    float4 v = ((const float4*)in_feat)[i];
    unsigned pk = 0;
    pk = __builtin_amdgcn_cvt_pk_fp8_f32(v.x, v.y, pk, false);
    pk = __builtin_amdgcn_cvt_pk_fp8_f32(v.z, v.w, pk, true);
    feat0[i] = pk;
  } else {
    int w2 = (b >= PREP_ZERO + PREP_CVT + PREP_W);
    int idx = (b - PREP_ZERO - PREP_CVT - (w2 ? PREP_W : 0)) * 256 + t;
    int n = idx >> 5, k0 = (idx & 31) * 4;   // Wt[n][k0..k0+3]
    int r = n >> 7, c = n & 127;
    const float* Wr = w2 ? W2 : W1;
    const float* Ws = w2 ? W2s : W1s;
    float v0, v1, v2, v3;
    if (r < NREL) {
      v0 = Wr[((size_t)(r * F + k0 + 0)) * F + c];
      v1 = Wr[((size_t)(r * F + k0 + 1)) * F + c];
      v2 = Wr[((size_t)(r * F + k0 + 2)) * F + c];
      v3 = Wr[((size_t)(r * F + k0 + 3)) * F + c];
    } else {
      v0 = Ws[(size_t)(k0 + 0) * F + c];
      v1 = Ws[(size_t)(k0 + 1) * F + c];
      v2 = Ws[(size_t)(k0 + 2) * F + c];
      v3 = Ws[(size_t)(k0 + 3) * F + c];
    }
    unsigned pk = 0;
    pk = __builtin_amdgcn_cvt_pk_fp8_f32(v0, v1, pk, false);
    pk = __builtin_amdgcn_cvt_pk_fp8_f32(v2, v3, pk, true);
    (w2 ? Wt2 : Wt1)[idx] = pk;
  }
}

// ======== fine sort: bucket segment -> CSR (counts from bcur) ===============
__global__ __launch_bounds__(512)
void k_fsort(const int* __restrict__ ebuf, const int* __restrict__ bcur,
             int* __restrict__ rowptr, int* __restrict__ edata) {
  __shared__ int cnt[512];
  __shared__ int pos[512];
  __shared__ int ws2[512];
  __shared__ int bc_s;
  const int b = blockIdx.x, t = threadIdx.x;
  // ---- global base = sum_{k<b} bcur[k] (bcur holds final bucket counts) ----
  int myc = (t < NBKT) ? bcur[t] : 0;
  ws2[t] = (t < b) ? myc : 0;
  if (t == b) bc_s = myc;
  __syncthreads();
  for (int off = 1; off < 512; off <<= 1) {
    int x = (t >= off) ? ws2[t - off] : 0;
    __syncthreads();
    ws2[t] += x;
    __syncthreads();
  }
  const int beg = ws2[511];
  const int cntb = bc_s;
  const int sbeg = b * SEG;  // segment start in ebuf

  cnt[t] = 0;
  __syncthreads();
  for (int e = t; e < cntb; e += 512)
    atomicAdd(&cnt[((unsigned)ebuf[sbeg + e]) >> 19], 1);
  __syncthreads();
  int myn = cnt[t];
  ws2[t] = myn;
  __syncthreads();
  for (int off = 1; off < 512; off <<= 1) {
    int x = (t >= off) ? ws2[t - off] : 0;
    __syncthreads();
    ws2[t] += x;
    __syncthreads();
  }
  pos[t] = ws2[t] - myn;
  __syncthreads();
  int node = (b << BSH) + t;
  if (node < NNODES) rowptr[node] = beg + pos[t];
  if (b == NBKT - 1 && t == 0) rowptr[NNODES] = NEDGES;
  __syncthreads();
  for (int e = t; e < cntb; e += 512) {
    int rec = ebuf[sbeg + e];
    int c = ((unsigned)rec) >> 19;
    int lrank = atomicAdd(&pos[c], 1);
    int srcv = (rec >> 3) & 0xFFFF;
    int etv = rec & 7;
    edata[beg + lrank] = srcv * NOUT + etv * F;  // byte offset in fp8 xrs
  }
}

// ====== GEMM: xrs[50000][1152](fp8) = A[50000][128] @ Wt^T  (fp8 MFMA) ======
// R20: full fp8 datapath. As/Bs 16KB each (LDS 33.5KB -> 4 blocks/CU).
// 8B-granular XOR swizzle; mfma_f32_16x16x32_fp8_fp8, swapped operands.
// Epilogue LDS-transpose stores (R16). doCsr blocks [0,196): CSR scatter.
__global__ __launch_bounds__(512, 8)
void gemm_xrs(const unsigned char* __restrict__ A,
              const unsigned char* __restrict__ Wt,
              unsigned char* __restrict__ xrs, int doCsr,
              const int* __restrict__ src, const int* __restrict__ dst,
              const int* __restrict__ et, int* __restrict__ bcur,
              int* __restrict__ ebuf) {
  __shared__ uint4 As[1024];  // 128 rows x 8 uint4 (fp8), xor-swizzled
  __shared__ uint4 Bs[1024];
  __shared__ int lhist[NBKT];
  __shared__ int lbase[NBKT];
  const int tid = threadIdx.x;

  if (doCsr && blockIdx.x < CSR_BLOCKS) {
    // ---- coarse scatter: record = (dst_local<<19)|(src<<3)|et ----
    if (tid < NBKT) lhist[tid] = 0;
    __syncthreads();
    int e0 = blockIdx.x * 4096;
    int rec[8], cc[8], lr[8];
#pragma unroll
    for (int i = 0; i < 8; ++i) {
      int e = e0 + tid + i * 512;
      if (e < NEDGES) {
        int d = dst[e];
        cc[i] = d >> BSH;
        rec[i] = ((d & 511) << 19) | (src[e] << 3) | et[e];
        lr[i] = atomicAdd(&lhist[cc[i]], 1);
      } else {
        cc[i] = -1;
      }
    }
    __syncthreads();
    if (tid < NBKT && lhist[tid] > 0) lbase[tid] = atomicAdd(&bcur[tid], lhist[tid]);
    __syncthreads();
#pragma unroll
    for (int i = 0; i < 8; ++i)
      if (cc[i] >= 0) ebuf[cc[i] * SEG + lbase[cc[i]] + lr[i]] = rec[i];
    return;
  }

  const int id = blockIdx.x - (doCsr ? CSR_BLOCKS : 0);
  const int x = id & 7, j = id >> 3;
  const int tile = (j / 9) * 8 + x;
  const int cb = j % 9;
  if (tile >= NTILES) return;
  const int row0 = tile * 128;

  const int lane = tid & 63;
  const int w = tid >> 6;           // 0..7
  const int i16 = lane & 15, q = lane >> 4;
  const int mbase = (w & 3) * 32, nbase = (w >> 2) * 64;

  // Stage fp8 tiles via global_load_lds: slot L (r=L>>3, chunk c8s=L&7)
  // receives source chunk c8s ^ (r&7)  (involution matches the read side).
#pragma unroll
  for (int i = 0; i < 2; ++i) {
    int L = tid + i * 512;
    int r = L >> 3, c8s = L & 7;
    int c8 = c8s ^ (r & 7);
    int agr = row0 + r; if (agr >= NNODES) agr = NNODES - 1;
    gll16((const void*)(A + (size_t)agr * F + c8 * 16), (void*)&As[L]);
    gll16((const void*)(Wt + ((size_t)cb * 128 + r) * F + c8 * 16), (void*)&Bs[L]);
  }
  __syncthreads();

  f32x4 acc[2][4];
#pragma unroll
  for (int a = 0; a < 2; ++a)
#pragma unroll
    for (int b = 0; b < 4; ++b) acc[a][b] = (f32x4)0.f;

  const char* Ab = (const char*)As;
  const char* Bb = (const char*)Bs;
#pragma unroll
  for (int c = 0; c < 4; ++c) {
    // lane holds 8 fp8 K-elems: k = c*32 + q*8 .. +7
    const int ch = c * 2 + (q >> 1);   // 16B chunk index of that K-slice
    const int h8 = (q & 1) << 3;       // 8B half within chunk
    long af[2], bfr[4];
#pragma unroll
    for (int mi = 0; mi < 2; ++mi) {
      int r = mbase + mi * 16 + i16;
      af[mi] = *(const long*)(Ab + r * 128 + ((ch ^ (r & 7)) << 4) + h8);
    }
#pragma unroll
    for (int ni = 0; ni < 4; ++ni) {
      int r = nbase + ni * 16 + i16;
      bfr[ni] = *(const long*)(Bb + r * 128 + ((ch ^ (r & 7)) << 4) + h8);
    }
    // Swapped operands: D[m=weight feature][n=node row]
#pragma unroll
    for (int mi = 0; mi < 2; ++mi)
#pragma unroll
      for (int ni = 0; ni < 4; ++ni)
        acc[mi][ni] = __builtin_amdgcn_mfma_f32_16x16x32_fp8_fp8(
            bfr[ni], af[mi], acc[mi][ni], 0, 0, 0);
  }

  // ---- Epilogue with LDS transpose (R16) ----
  unsigned pkv[2][4];
#pragma unroll
  for (int mi = 0; mi < 2; ++mi)
#pragma unroll
    for (int ni = 0; ni < 4; ++ni) {
      f32x4 v = acc[mi][ni];
      unsigned pk = 0;
      pk = __builtin_amdgcn_cvt_pk_fp8_f32(v[0], v[1], pk, false);
      pk = __builtin_amdgcn_cvt_pk_fp8_f32(v[2], v[3], pk, true);
      pkv[mi][ni] = pk;
    }

  __syncthreads();  // all waves done reading As; reuse As as staging (16KB)
  unsigned* sbuf = (unsigned*)As;  // [128 nodes][32 dwords] = 16KB
  {
    const int dbase = (nbase >> 2) + q;
#pragma unroll
    for (int mi = 0; mi < 2; ++mi) {
      int nl = mbase + mi * 16 + i16;
      int sw = (nl & 7) << 2;
      int vb_ = nl * 32;
#pragma unroll
      for (int ni = 0; ni < 4; ++ni)
        sbuf[vb_ + ((dbase + ni * 4) ^ sw)] = pkv[mi][ni];
    }
  }
  __syncthreads();

#pragma unroll
  for (int k = 0; k < 2; ++k) {
    int nl = k * 64 + (tid >> 3);
    int ch = tid & 7;
    int d0 = (ch * 4) ^ ((nl & 7) << 2);
    uint4 v = *(const uint4*)&sbuf[nl * 32 + d0];
    int row = row0 + nl;
    if (row < NNODES)
      *(uint4*)(xrs + (size_t)row * NOUT + cb * 128 + ch * 16) = v;
  }
}

// ========== aggregate: h_next[dst] = relu(sum_e xrs[edata] + self + b) ======
// R24: 2 nodes per wave (independent 32-lane halves) -> 2x the latency
// chains per wave vs R21. Per half: 16 lanes x uint2 (8B) covers a full
// 128B xrs row; 2 groups/half -> 2 edges per wave-instr per node, 8-deep
// batches = 16 edges in flight per node. R23 lesson: xrs gathers are
// HBM-latency-bound (stores don't L3-allocate; FETCH=53MB), so MLP is the
// lever. 6250 blocks x 8 nodes. hout: fp8 h store. pooled_p: LDS-reduce
// (8 rows) + 64-slot-spread atomics.
__global__ __launch_bounds__(256)
void k_aggregate(const unsigned char* __restrict__ xrs,
                 const int* __restrict__ rowptr, const int* __restrict__ edata,
                 const float* __restrict__ bias, unsigned char* __restrict__ hout,
                 float* __restrict__ pooled_p) {
  __shared__ float red[8][128];
  const int wv = threadIdx.x >> 6;
  const int lane = threadIdx.x & 63;
  const int h = lane >> 5;            // which of the wave's 2 nodes
  const int sl = lane & 31;
  const int g = sl >> 4, s = sl & 15; // group within half, 16-lane slot
  const int node = blockIdx.x * 8 + wv * 2 + h;
  const int beg = rowptr[node], end = rowptr[node + 1];

  float a[8];
#pragma unroll
  for (int j = 0; j < 8; ++j) a[j] = 0.f;

  // self-loop row (r=8), counted once per node by group 0
  if (g == 0) {
    uint2 sv = *(const uint2*)(xrs + (size_t)node * NOUT + NREL * F + s * 8);
    f32x2 l0 = __builtin_amdgcn_cvt_pk_f32_fp8(sv.x, false);
    f32x2 h0 = __builtin_amdgcn_cvt_pk_f32_fp8(sv.x, true);
    f32x2 l1 = __builtin_amdgcn_cvt_pk_f32_fp8(sv.y, false);
    f32x2 h1 = __builtin_amdgcn_cvt_pk_f32_fp8(sv.y, true);
    a[0] += l0[0]; a[1] += l0[1]; a[2] += h0[0]; a[3] += h0[1];
    a[4] += l1[0]; a[5] += l1[1]; a[6] += h1[0]; a[7] += h1[1];
  }

  for (int base = beg; base < end; base += 32) {
    int cnt = end - base; if (cnt > 32) cnt = 32;
    int my = (base + sl < end) ? edata[base + sl] : 0;
    int pairs = cnt >> 1;
    int p = 0;
    for (; p + 8 <= pairs; p += 8) {
      uint2 v[8];
#pragma unroll
      for (int k = 0; k < 8; ++k) {
        int off = __shfl(my, 2 * (p + k) + g, 32);
        v[k] = *(const uint2*)(xrs + (size_t)off + s * 8);
      }
#pragma unroll
      for (int k = 0; k < 8; ++k) {
        f32x2 l0 = __builtin_amdgcn_cvt_pk_f32_fp8(v[k].x, false);
        f32x2 h0 = __builtin_amdgcn_cvt_pk_f32_fp8(v[k].x, true);
        f32x2 l1 = __builtin_amdgcn_cvt_pk_f32_fp8(v[k].y, false);
        f32x2 h1 = __builtin_amdgcn_cvt_pk_f32_fp8(v[k].y, true);
        a[0] += l0[0]; a[1] += l0[1]; a[2] += h0[0]; a[3] += h0[1];
        a[4] += l1[0]; a[5] += l1[1]; a[6] += h1[0]; a[7] += h1[1];
      }
    }
    for (; p < pairs; ++p) {
      int off = __shfl(my, 2 * p + g, 32);
      uint2 vv = *(const uint2*)(xrs + (size_t)off + s * 8);
      f32x2 l0 = __builtin_amdgcn_cvt_pk_f32_fp8(vv.x, false);
      f32x2 h0 = __builtin_amdgcn_cvt_pk_f32_fp8(vv.x, true);
      f32x2 l1 = __builtin_amdgcn_cvt_pk_f32_fp8(vv.y, false);
      f32x2 h1 = __builtin_amdgcn_cvt_pk_f32_fp8(vv.y, true);
      a[0] += l0[0]; a[1] += l0[1]; a[2] += h0[0]; a[3] += h0[1];
      a[4] += l1[0]; a[5] += l1[1]; a[6] += h1[0]; a[7] += h1[1];
    }
    if (cnt & 1) {
      int off = __shfl(my, cnt - 1, 32);
      if (g == 0) {
        uint2 vv = *(const uint2*)(xrs + (size_t)off + s * 8);
        f32x2 l0 = __builtin_amdgcn_cvt_pk_f32_fp8(vv.x, false);
        f32x2 h0 = __builtin_amdgcn_cvt_pk_f32_fp8(vv.x, true);
        f32x2 l1 = __builtin_amdgcn_cvt_pk_f32_fp8(vv.y, false);
        f32x2 h1 = __builtin_amdgcn_cvt_pk_f32_fp8(vv.y, true);
        a[0] += l0[0]; a[1] += l0[1]; a[2] += h0[0]; a[3] += h0[1];
        a[4] += l1[0]; a[5] += l1[1]; a[6] += h1[0]; a[7] += h1[1];
      }
    }
  }

  // merge the two group partial sums within each half (bit 4)
#pragma unroll
  for (int j = 0; j < 8; ++j) a[j] += __shfl_xor(a[j], 16, 64);

  float4 bb0 = ((const float4*)bias)[s * 2];
  float4 bb1 = ((const float4*)bias)[s * 2 + 1];
  a[0] = fmaxf(a[0] + bb0.x, 0.f);
  a[1] = fmaxf(a[1] + bb0.y, 0.f);
  a[2] = fmaxf(a[2] + bb0.z, 0.f);
  a[3] = fmaxf(a[3] + bb0.w, 0.f);
  a[4] = fmaxf(a[4] + bb1.x, 0.f);
  a[5] = fmaxf(a[5] + bb1.y, 0.f);
  a[6] = fmaxf(a[6] + bb1.z, 0.f);
  a[7] = fmaxf(a[7] + bb1.w, 0.f);

  if (hout) {
    if (g == 0) {
      uint2 pk;
      unsigned p0 = 0;
      p0 = __builtin_amdgcn_cvt_pk_fp8_f32(a[0], a[1], p0, false);
      p0 = __builtin_amdgcn_cvt_pk_fp8_f32(a[2], a[3], p0, true);
      unsigned p1 = 0;
      p1 = __builtin_amdgcn_cvt_pk_fp8_f32(a[4], a[5], p1, false);
      p1 = __builtin_amdgcn_cvt_pk_fp8_f32(a[6], a[7], p1, true);
      pk.x = p0; pk.y = p1;
      ((uint2*)(hout + (size_t)node * F))[s] = pk;
    }
  } else {
    if (g == 0) {
#pragma unroll
      for (int j = 0; j < 8; ++j) red[wv * 2 + h][s * 8 + j] = a[j];
    }
    __syncthreads();
    if (threadIdx.x < 128) {
      float sm = 0.f;
#pragma unroll
      for (int r = 0; r < 8; ++r) sm += red[r][threadIdx.x];
      atomicAdd(&pooled_p[(blockIdx.x & 63) * 128 + threadIdx.x], sm);
    }
  }
}

// ================== final: reduce 64x128 partials + fc + sigmoid ============
__global__ __launch_bounds__(128)
void k_final(const float* __restrict__ pooled_p, const float* __restrict__ fcw,
             const float* __restrict__ fcb, float* __restrict__ out) {
  __shared__ float s[128];
  int t = threadIdx.x;
  float acc = 0.f;
#pragma unroll 8
  for (int k = 0; k < 64; ++k) acc += pooled_p[k * 128 + t];
  s[t] = acc * (1.0f / (float)NNODES) * fcw[t];
  __syncthreads();
  if (t == 0) {
    float v = 0.f;
    for (int i = 0; i < 128; ++i) v += s[i];
    v += fcb[0];
    out[0] = 1.f / (1.f + expf(-v));
  }
}

// ============================================================================
extern "C" void kernel_launch(void* const* d_in, const int* in_sizes, int n_in,
                              void* d_out, int out_size, void* d_ws, size_t ws_size,
                              hipStream_t stream) {
  const float* in_feat = (const float*)d_in[0];
  const float* W1      = (const float*)d_in[1];
  const float* W1s     = (const float*)d_in[2];
  const float* b1      = (const float*)d_in[3];
  const float* W2      = (const float*)d_in[4];
  const float* W2s     = (const float*)d_in[5];
  const float* b2      = (const float*)d_in[6];
  const float* fcw     = (const float*)d_in[7];
  const float* fcb     = (const float*)d_in[8];
  const int*   src     = (const int*)d_in[9];
  const int*   dst     = (const int*)d_in[10];
  const int*   et      = (const int*)d_in[11];
  float* out = (float*)d_out;

  // Workspace (~80 MB)
  unsigned char* xrs = (unsigned char*)d_ws;              // [50000][1152] fp8
  unsigned char* feat0 = xrs + (size_t)NNODES * NOUT;     // [50000][128] fp8
  unsigned char* h1  = feat0 + (size_t)NNODES * F;        // [50000][128] fp8
  unsigned char* Wt1 = h1 + (size_t)NNODES * F;           // [1152][128] fp8
  unsigned char* Wt2 = Wt1 + (size_t)NOUT * F;            // [1152][128] fp8
  float* pooled_p = (float*)(Wt2 + (size_t)NOUT * F);     // [64][128]
  int*   bcur   = (int*)(pooled_p + 64 * 128);            // [NBKT+1]
  int*   rowptr = bcur + NBKT + 1;                        // [NNODES+1]
  int*   ebuf   = rowptr + NNODES + 2;                    // [NBKT*SEG]
  int*   edata  = ebuf + NBKT * SEG;                      // [NEDGES]

  // fused prep: zero(pooled_p,bcur) | feat cvt fp8 | weight prep x2
  k_prep<<<PREP_ZERO + PREP_CVT + 2 * PREP_W, 256, 0, stream>>>(
      in_feat, (unsigned*)feat0, W1, W1s, (unsigned*)Wt1,
      W2, W2s, (unsigned*)Wt2, pooled_p, bcur);

  const int aggBlocks = NNODES / 8;                    // 6250

  // Layer 1 GEMM with CSR-scatter fused (scatter hidden under GEMM)
  gemm_xrs<<<CSR_BLOCKS + GEMM_BLOCKS, 512, 0, stream>>>(
      feat0, Wt1, xrs, 1, src, dst, et, bcur, ebuf);
  k_fsort<<<NBKT, 512, 0, stream>>>(ebuf, bcur, rowptr, edata);
  k_aggregate<<<aggBlocks, 256, 0, stream>>>(xrs, rowptr, edata, b1, h1, nullptr);
  // Layer 2 (pooling fused into aggregate; h2 never materialized)
  gemm_xrs<<<GEMM_BLOCKS, 512, 0, stream>>>(
      h1, Wt2, xrs, 0, src, dst, et, bcur, ebuf);
  k_aggregate<<<aggBlocks, 256, 0, stream>>>(xrs, rowptr, edata, b2, nullptr, pooled_p);

  // Reduce partials + fc + sigmoid
  k_final<<<1, 128, 0, stream>>>(pooled_p, fcw, fcb, out);
}